// Round 5
// baseline (22.456 us; speedup 1.0000x reference)
//
#include <hip/hip_runtime.h>
#include <hip/hip_fp16.h>

#define IN_F   4096
#define OUT_F  4096
#define BATCH  32
#define NGPR   512          // groups per output row
#define BN     16           // output rows per block
#define NW     8            // waves per block

typedef float f32x4  __attribute__((ext_vector_type(4)));
typedef short short8 __attribute__((ext_vector_type(8)));

__device__ __forceinline__ unsigned short f2bf_u(float f) {
    return __builtin_bit_cast(unsigned short, (__bf16)f);   // RNE via v_cvt
}

__device__ __forceinline__ void gload16(const void* gsrc, void* lds) {
    __builtin_amdgcn_global_load_lds(
        (const __attribute__((address_space(1))) void*)gsrc,
        (__attribute__((address_space(3))) void*)lds, 16, 0, 0);
}

// ---- pack x[32][4096] fp32 -> A-fragment-layout bf16 in d_ws ----
// apk unit u = (a*128 + s)*64 + q*16 + cl  holds bf16 x[a*16+cl][s*32+q*8 .. +8]
__global__ __launch_bounds__(128)
void pack_x_kernel(const float* __restrict__ x, unsigned short* __restrict__ apk)
{
    const int tau = blockIdx.x * 128 + threadIdx.x;   // 0..16383
    const int row = tau >> 9;                         // 0..31
    const int c   = tau & 511;                        // 8-float chunk within row
    const float4 lo = *reinterpret_cast<const float4*>(&x[row * IN_F + c * 8]);
    const float4 hi = *reinterpret_cast<const float4*>(&x[row * IN_F + c * 8 + 4]);
    union { unsigned short us[8]; uint4 v; } pk;
    pk.us[0] = f2bf_u(lo.x); pk.us[1] = f2bf_u(lo.y);
    pk.us[2] = f2bf_u(lo.z); pk.us[3] = f2bf_u(lo.w);
    pk.us[4] = f2bf_u(hi.x); pk.us[5] = f2bf_u(hi.y);
    pk.us[6] = f2bf_u(hi.z); pk.us[7] = f2bf_u(hi.w);
    const int a = row >> 4, cl = row & 15, s = c >> 2, q = c & 3;
    const int unit = (a * 128 + s) * 64 + q * 16 + cl;
    *reinterpret_cast<uint4*>(&apk[unit * 8]) = pk.v;
}

template<bool PACKED>
__global__ __launch_bounds__(512, 2)
void l3b_main(const float* __restrict__ x,
              const int* __restrict__ wq3,
              const void* __restrict__ wnorm_raw,
              const float* __restrict__ bias,
              float* __restrict__ out,
              const unsigned short* __restrict__ apk)
{
    // q raw bytes, 16B-block row-interleaved: LDS block B=bcol*16+row holds
    // global bytes [row*6144 + bcol*16, +16) of this block's 16-row q panel.
    __shared__ unsigned int qls[24576];   // 96 KB
    __shared__ unsigned int nls[8192];    // 32 KB (norms raw, same interleave)
    __shared__ float red[NW][BATCH][17];  // 17.4 KB

    const int tid   = threadIdx.x;
    const int w     = tid >> 6;
    const int lane  = tid & 63;
    const int nbase = blockIdx.x * BN;

    const int q  = lane >> 4;   // 0..3
    const int cl = lane & 15;   // 0..15

    // ---- weight_norm dtype probe (deterministic, wave-uniform) ----
    // 0 = float32, 1 = float16 (raw), 2 = bfloat16
    const unsigned short* wn16  = (const unsigned short*)wnorm_raw;
    const float*          wn32  = (const float*)wnorm_raw;
    const unsigned int*   wnu32 = (const unsigned int*)wnorm_raw;
    int mode;
    {
        const unsigned short h = wn16[lane];
        const float v16 = __half2float(__builtin_bit_cast(__half, h));
        const float vbf = __builtin_bit_cast(float, (unsigned int)h << 16);
        const float v32 = wn32[lane];
        const int c16 = __popcll(__ballot(v16 > 0.0095f && v16 < 1.0005f));
        const int cbf = __popcll(__ballot(vbf > 0.0095f && vbf < 1.0005f));
        const int c32 = __popcll(__ballot(v32 > 0.0095f && v32 < 1.0005f));
        if (c16 >= c32 && c16 >= cbf) {
            mode = 1;
        } else if (c32 > cbf + 8) {
            mode = 0;
        } else if (cbf > c32 + 8) {
            mode = 2;
        } else {
            const int z = __popcll(__ballot((wnu32[lane] & 0x1FFFu) == 0u));
            mode = (z >= 48) ? 0 : 2;
        }
    }

    // ---- async staging: q chunk0 | norms chunk0 | q chunk1 | norms chunk1 ----
    const int* qgbase = wq3 + (long)nbase * 1536;   // 16 rows x 1536 dwords
    #pragma unroll
    for (int j = 0; j < 6; ++j) {                   // q chunk0: B in [0,3072)
        const int B = j * 512 + tid;
        gload16(qgbase + (B & 15) * 1536 + (B >> 4) * 4, &qls[B * 4]);
    }
    if (mode == 0) {
        const float* nb = wn32 + (long)nbase * NGPR;
        #pragma unroll
        for (int j = 0; j < 2; ++j) {               // norms c0: Bn in [0,1024)
            const int B = j * 512 + tid;
            gload16(nb + (B & 15) * 512 + (B >> 4) * 4, &nls[B * 4]);
        }
    } else {
        const unsigned short* nb = wn16 + (long)nbase * NGPR;
        const int B = tid;                          // norms c0: Bn in [0,512)
        gload16(nb + (B & 15) * 512 + (B >> 4) * 8, (unsigned short*)nls + B * 8);
    }
    #pragma unroll
    for (int j = 6; j < 12; ++j) {                  // q chunk1: B in [3072,6144)
        const int B = j * 512 + tid;
        gload16(qgbase + (B & 15) * 1536 + (B >> 4) * 4, &qls[B * 4]);
    }
    if (mode == 0) {
        const float* nb = wn32 + (long)nbase * NGPR;
        #pragma unroll
        for (int j = 2; j < 4; ++j) {               // norms c1: Bn in [1024,2048)
            const int B = j * 512 + tid;
            gload16(nb + (B & 15) * 512 + (B >> 4) * 4, &nls[B * 4]);
        }
    } else {
        const unsigned short* nb = wn16 + (long)nbase * NGPR;
        const int B = 512 + tid;                    // norms c1: Bn in [512,1024)
        gload16(nb + (B & 15) * 512 + (B >> 4) * 8, (unsigned short*)nls + B * 8);
    }

    f32x4 acc0 = {0.f, 0.f, 0.f, 0.f};
    f32x4 acc1 = {0.f, 0.f, 0.f, 0.f};

    // one K-step: group g = s*4+q, row cl
    auto body = [&](int s) {
        const int g  = s * 4 + q;
        const int b0 = g * 12;          // byte-in-row of the group's dword0
        const unsigned p0 = qls[(( b0      >> 4) << 6) + (cl << 2) + (( b0       & 15) >> 2)];
        const unsigned p1 = qls[(((b0 + 4) >> 4) << 6) + (cl << 2) + (((b0 + 4)  & 15) >> 2)];
        const unsigned p2 = qls[(((b0 + 8) >> 4) << 6) + (cl << 2) + (((b0 + 8)  & 15) >> 2)];
        const unsigned val = (p0 & 0xFFu) | ((p1 & 0xFFu) << 8) | ((p2 & 0xFFu) << 16);

        float n;
        if (mode == 0) {
            n = ((const float*)nls)[((g >> 2) << 6) + (cl << 2) + (g & 3)];
        } else {
            const unsigned short u =
                ((const unsigned short*)nls)[((g >> 3) << 7) + (cl << 3) + (g & 7)];
            n = (mode == 1) ? __half2float(__builtin_bit_cast(__half, u))
                            : __builtin_bit_cast(float, (unsigned)u << 16);
        }
        const float av = n * 0.285714285714285714f;   // 2n/7
        union { unsigned short us[8]; short8 v; } B;
        #pragma unroll
        for (int e = 0; e < 8; ++e) {
            const float qf = (float)((val >> (3 * e)) & 7u);
            B.us[e] = f2bf_u(fmaf(qf, av, -n));
        }

        short8 A0, A1;
        if (PACKED) {
            A0 = *reinterpret_cast<const short8*>(&apk[(s * 64 + lane) * 8]);
            A1 = *reinterpret_cast<const short8*>(&apk[((128 + s) * 64 + lane) * 8]);
        } else {
            const int kg = s * 32 + q * 8;
            const float4 a0lo = *reinterpret_cast<const float4*>(&x[cl        * IN_F + kg]);
            const float4 a0hi = *reinterpret_cast<const float4*>(&x[cl        * IN_F + kg + 4]);
            const float4 a1lo = *reinterpret_cast<const float4*>(&x[(cl + 16) * IN_F + kg]);
            const float4 a1hi = *reinterpret_cast<const float4*>(&x[(cl + 16) * IN_F + kg + 4]);
            union { unsigned short us[8]; short8 v; } U0, U1;
            U0.us[0] = f2bf_u(a0lo.x); U0.us[1] = f2bf_u(a0lo.y);
            U0.us[2] = f2bf_u(a0lo.z); U0.us[3] = f2bf_u(a0lo.w);
            U0.us[4] = f2bf_u(a0hi.x); U0.us[5] = f2bf_u(a0hi.y);
            U0.us[6] = f2bf_u(a0hi.z); U0.us[7] = f2bf_u(a0hi.w);
            U1.us[0] = f2bf_u(a1lo.x); U1.us[1] = f2bf_u(a1lo.y);
            U1.us[2] = f2bf_u(a1lo.z); U1.us[3] = f2bf_u(a1lo.w);
            U1.us[4] = f2bf_u(a1hi.x); U1.us[5] = f2bf_u(a1hi.y);
            U1.us[6] = f2bf_u(a1hi.z); U1.us[7] = f2bf_u(a1hi.w);
            A0 = U0.v; A1 = U1.v;
        }

        acc0 = __builtin_amdgcn_mfma_f32_16x16x32_bf16(A0, B.v, acc0, 0, 0, 0);
        acc1 = __builtin_amdgcn_mfma_f32_16x16x32_bf16(A1, B.v, acc1, 0, 0, 0);
    };

    // ---- chunk 0: wait own c0 issues (counted — c1 stays in flight) ----
    if (mode == 0) asm volatile("s_waitcnt vmcnt(8)" ::: "memory");
    else           asm volatile("s_waitcnt vmcnt(7)" ::: "memory");
    __builtin_amdgcn_s_barrier();

    #pragma unroll 4
    for (int i = 0; i < 8; ++i) body(w * 8 + i);

    // ---- chunk 1 ----
    asm volatile("s_waitcnt vmcnt(0)" ::: "memory");
    __builtin_amdgcn_s_barrier();

    #pragma unroll 4
    for (int i = 0; i < 8; ++i) body(64 + w * 8 + i);

    // ---- cross-wave K-reduction + bias + store ----
    #pragma unroll
    for (int i = 0; i < 4; ++i) {
        red[w][q * 4 + i][cl]      = acc0[i];
        red[w][16 + q * 4 + i][cl] = acc1[i];
    }
    __syncthreads();
    {
        const int m  = tid >> 4;   // 0..31
        const int nl = tid & 15;
        float ssum = 0.f;
        #pragma unroll
        for (int wv = 0; wv < NW; ++wv) ssum += red[wv][m][nl];
        out[m * OUT_F + nbase + nl] = ssum + bias[nbase + nl];
    }
}

extern "C" void kernel_launch(void* const* d_in, const int* in_sizes, int n_in,
                              void* d_out, int out_size, void* d_ws, size_t ws_size,
                              hipStream_t stream) {
    const float* x    = (const float*)d_in[0];
    const int*   wq3  = (const int*)d_in[1];
    const void*  wn   = (const void*)d_in[2];
    const float* bias = (const float*)d_in[3];
    float*       out  = (float*)d_out;

    if (ws_size >= (size_t)(2 * 128 * 64 * 8 * 2)) {   // 256 KB packed-A
        unsigned short* apk = (unsigned short*)d_ws;
        pack_x_kernel<<<dim3(128), dim3(128), 0, stream>>>(x, apk);
        l3b_main<true><<<dim3(OUT_F / BN), dim3(512), 0, stream>>>(x, wq3, wn, bias, out, apk);
    } else {
        l3b_main<false><<<dim3(OUT_F / BN), dim3(512), 0, stream>>>(x, wq3, wn, bias, out, nullptr);
    }
}

// Round 6
// 19.802 us; speedup vs baseline: 1.1340x; 1.1340x over previous
//
#include <hip/hip_runtime.h>
#include <hip/hip_fp16.h>

#define IN_F   4096
#define OUT_F  4096
#define BATCH  32
#define NGPR   512          // groups per output row
#define BN     16           // output rows per block tile
#define NW     4            // waves per block
#define QP     260          // qw pitch (dwords): 256 + 4 pad -> bank stride 4
#define NP     260          // nrm pitch (floats)

typedef float f32x4  __attribute__((ext_vector_type(4)));
typedef short short8 __attribute__((ext_vector_type(8)));

__device__ __forceinline__ unsigned short f2bf_u(float f) {
    return __builtin_bit_cast(unsigned short, (__bf16)f);   // RNE via v_cvt
}

// ---- pack x[32][4096] fp32 -> A-fragment-layout bf16 in d_ws ----
// apk unit u = (a*128 + s)*64 + q*16 + cl  holds bf16 x[a*16+cl][s*32+q*8 .. +8]
__global__ __launch_bounds__(256)
void pack_x_kernel(const float* __restrict__ x, unsigned short* __restrict__ apk)
{
    const int tau = blockIdx.x * 256 + threadIdx.x;   // 0..16383
    const int row = tau >> 9;                         // 0..31
    const int c   = tau & 511;                        // 8-float chunk within row
    const float4 lo = *reinterpret_cast<const float4*>(&x[row * IN_F + c * 8]);
    const float4 hi = *reinterpret_cast<const float4*>(&x[row * IN_F + c * 8 + 4]);
    union { unsigned short us[8]; uint4 v; } pk;
    pk.us[0] = f2bf_u(lo.x); pk.us[1] = f2bf_u(lo.y);
    pk.us[2] = f2bf_u(lo.z); pk.us[3] = f2bf_u(lo.w);
    pk.us[4] = f2bf_u(hi.x); pk.us[5] = f2bf_u(hi.y);
    pk.us[6] = f2bf_u(hi.z); pk.us[7] = f2bf_u(hi.w);
    const int a = row >> 4, cl = row & 15, s = c >> 2, q = c & 3;
    const int unit = (a * 128 + s) * 64 + q * 16 + cl;
    *reinterpret_cast<uint4*>(&apk[unit * 8]) = pk.v;
}

// grid 512: block b -> output tile nb = (b>>1)*16, K-half kh = b&1 (K 2048 each)
template<bool PACKED>
__global__ __launch_bounds__(256, 3)
void l3b_main(const float* __restrict__ x,
              const int* __restrict__ wq3,
              const void* __restrict__ wnorm_raw,
              const float* __restrict__ bias,
              float* __restrict__ out,
              const unsigned short* __restrict__ apk)
{
    __shared__ unsigned int qw[BN][QP];   // packed 24-bit group words (K-half)
    __shared__ float        nrm[BN][NP];  // per-group scales fp32 (K-half)
    __shared__ float        red[NW][BATCH][17];

    const int tid   = threadIdx.x;
    const int w     = tid >> 6;
    const int lane  = tid & 63;
    const int nbase = (blockIdx.x >> 1) * BN;
    const int kh    = blockIdx.x & 1;

    const int q  = lane >> 4;   // 0..3
    const int cl = lane & 15;   // 0..15

    // ---- weight_norm dtype probe (deterministic, wave-uniform) ----
    // 0 = float32, 1 = float16 (raw), 2 = bfloat16
    const unsigned short* wn16  = (const unsigned short*)wnorm_raw;
    const float*          wn32  = (const float*)wnorm_raw;
    const unsigned int*   wnu32 = (const unsigned int*)wnorm_raw;
    int mode;
    {
        const unsigned short h = wn16[lane];
        const float v16 = __half2float(__builtin_bit_cast(__half, h));
        const float vbf = __builtin_bit_cast(float, (unsigned int)h << 16);
        const float v32 = wn32[lane];
        const int c16 = __popcll(__ballot(v16 > 0.0095f && v16 < 1.0005f));
        const int cbf = __popcll(__ballot(vbf > 0.0095f && vbf < 1.0005f));
        const int c32 = __popcll(__ballot(v32 > 0.0095f && v32 < 1.0005f));
        if (c16 >= c32 && c16 >= cbf) {
            mode = 1;
        } else if (c32 > cbf + 8) {
            mode = 0;
        } else if (cbf > c32 + 8) {
            mode = 2;
        } else {
            const int z = __popcll(__ballot((wnu32[lane] & 0x1FFFu) == 0u));
            mode = (z >= 48) ? 0 : 2;
        }
    }

    // ---- stage norms -> fp32 LDS (16 rows x 256 groups of this K-half) ----
    if (mode == 0) {
        const float* nb = wn32 + (long)nbase * NGPR + kh * 256;
        #pragma unroll
        for (int j = 0; j < 4; ++j) {
            const int e = j * 1024 + tid * 4;
            const int row = e >> 8, col = e & 255;
            const float4 v = *reinterpret_cast<const float4*>(nb + (long)row * NGPR + col);
            *reinterpret_cast<float4*>(&nrm[row][col]) = v;
        }
    } else {
        const unsigned short* nb = wn16 + (long)nbase * NGPR + kh * 256;
        #pragma unroll
        for (int j = 0; j < 2; ++j) {
            const int e = j * 2048 + tid * 8;
            const int row = e >> 8, col = e & 255;
            union { unsigned short us[8]; uint4 v; } u;
            u.v = *reinterpret_cast<const uint4*>(nb + (long)row * NGPR + col);
            float4 f0, f1;
            if (mode == 1) {
                f0.x = __half2float(__builtin_bit_cast(__half, u.us[0]));
                f0.y = __half2float(__builtin_bit_cast(__half, u.us[1]));
                f0.z = __half2float(__builtin_bit_cast(__half, u.us[2]));
                f0.w = __half2float(__builtin_bit_cast(__half, u.us[3]));
                f1.x = __half2float(__builtin_bit_cast(__half, u.us[4]));
                f1.y = __half2float(__builtin_bit_cast(__half, u.us[5]));
                f1.z = __half2float(__builtin_bit_cast(__half, u.us[6]));
                f1.w = __half2float(__builtin_bit_cast(__half, u.us[7]));
            } else {
                f0.x = __builtin_bit_cast(float, (unsigned)u.us[0] << 16);
                f0.y = __builtin_bit_cast(float, (unsigned)u.us[1] << 16);
                f0.z = __builtin_bit_cast(float, (unsigned)u.us[2] << 16);
                f0.w = __builtin_bit_cast(float, (unsigned)u.us[3] << 16);
                f1.x = __builtin_bit_cast(float, (unsigned)u.us[4] << 16);
                f1.y = __builtin_bit_cast(float, (unsigned)u.us[5] << 16);
                f1.z = __builtin_bit_cast(float, (unsigned)u.us[6] << 16);
                f1.w = __builtin_bit_cast(float, (unsigned)u.us[7] << 16);
            }
            *reinterpret_cast<float4*>(&nrm[row][col])     = f0;
            *reinterpret_cast<float4*>(&nrm[row][col + 4]) = f1;
        }
    }

    // ---- stage packed q-words: 16 rows x 256 groups, 4:1 compaction ----
    {
        const int* qgbase = wq3 + (long)nbase * 1536 + kh * 768;   // dwords
        #pragma unroll
        for (int r2 = 0; r2 < 4; ++r2) {
            const int row = r2 * 4 + (tid >> 6);
            const int cb  = (tid & 63) * 12;                       // dword in row-half
            const int* p = qgbase + (long)row * 1536 + cb;
            const int4 ia = *reinterpret_cast<const int4*>(p);
            const int4 ib = *reinterpret_cast<const int4*>(p + 4);
            const int4 ic = *reinterpret_cast<const int4*>(p + 8);
            uint4 wd;
            wd.x = (unsigned)(ia.x | (ia.y << 8) | (ia.z << 16));
            wd.y = (unsigned)(ia.w | (ib.x << 8) | (ib.y << 16));
            wd.z = (unsigned)(ib.z | (ib.w << 8) | (ic.x << 16));
            wd.w = (unsigned)(ic.y | (ic.z << 8) | (ic.w << 16));
            *reinterpret_cast<uint4*>(&qw[row][(tid & 63) * 4]) = wd;
        }
    }

    __syncthreads();

    // ---- compute: wave w owns local ksteps s = w*16 .. w*16+15 (K=512) ----
    f32x4 acc0 = {0.f, 0.f, 0.f, 0.f};
    f32x4 acc1 = {0.f, 0.f, 0.f, 0.f};

    #pragma unroll 4
    for (int i = 0; i < 16; ++i) {
        const int s = w * 16 + i;       // local k-step 0..63
        const int g = s * 4 + q;        // local group 0..255

        const unsigned int qv = qw[cl][g];
        const float n  = nrm[cl][g];
        const float av = n * 0.285714285714285714f;   // 2n/7
        union { unsigned short us[8]; short8 v; } B;
        #pragma unroll
        for (int e = 0; e < 8; ++e) {
            const float qf = (float)((qv >> (3 * e)) & 7u);
            B.us[e] = f2bf_u(fmaf(qf, av, -n));
        }

        const int sg = kh * 64 + s;     // global k-step
        short8 A0, A1;
        if (PACKED) {
            A0 = *reinterpret_cast<const short8*>(&apk[(sg * 64 + lane) * 8]);
            A1 = *reinterpret_cast<const short8*>(&apk[((128 + sg) * 64 + lane) * 8]);
        } else {
            const int kg = sg * 32 + q * 8;
            const float4 a0lo = *reinterpret_cast<const float4*>(&x[cl        * IN_F + kg]);
            const float4 a0hi = *reinterpret_cast<const float4*>(&x[cl        * IN_F + kg + 4]);
            const float4 a1lo = *reinterpret_cast<const float4*>(&x[(cl + 16) * IN_F + kg]);
            const float4 a1hi = *reinterpret_cast<const float4*>(&x[(cl + 16) * IN_F + kg + 4]);
            union { unsigned short us[8]; short8 v; } U0, U1;
            U0.us[0] = f2bf_u(a0lo.x); U0.us[1] = f2bf_u(a0lo.y);
            U0.us[2] = f2bf_u(a0lo.z); U0.us[3] = f2bf_u(a0lo.w);
            U0.us[4] = f2bf_u(a0hi.x); U0.us[5] = f2bf_u(a0hi.y);
            U0.us[6] = f2bf_u(a0hi.z); U0.us[7] = f2bf_u(a0hi.w);
            U1.us[0] = f2bf_u(a1lo.x); U1.us[1] = f2bf_u(a1lo.y);
            U1.us[2] = f2bf_u(a1lo.z); U1.us[3] = f2bf_u(a1lo.w);
            U1.us[4] = f2bf_u(a1hi.x); U1.us[5] = f2bf_u(a1hi.y);
            U1.us[6] = f2bf_u(a1hi.z); U1.us[7] = f2bf_u(a1hi.w);
            A0 = U0.v; A1 = U1.v;
        }

        acc0 = __builtin_amdgcn_mfma_f32_16x16x32_bf16(A0, B.v, acc0, 0, 0, 0);
        acc1 = __builtin_amdgcn_mfma_f32_16x16x32_bf16(A1, B.v, acc1, 0, 0, 0);
    }

    // ---- cross-wave K-reduction + bias + atomic partial-sum store ----
    #pragma unroll
    for (int i = 0; i < 4; ++i) {
        red[w][q * 4 + i][cl]      = acc0[i];
        red[w][16 + q * 4 + i][cl] = acc1[i];
    }
    __syncthreads();
    {
        const int m  = tid >> 4;   // 0..15
        const int nl = tid & 15;
        float s1 = 0.f, s2 = 0.f;
        #pragma unroll
        for (int wv = 0; wv < NW; ++wv) {
            s1 += red[wv][m][nl];
            s2 += red[wv][m + 16][nl];
        }
        const float b = (kh == 0) ? bias[nbase + nl] : 0.0f;
        atomicAdd(&out[m * OUT_F + nbase + nl], s1 + b);
        atomicAdd(&out[(m + 16) * OUT_F + nbase + nl], s2 + b);
    }
}

extern "C" void kernel_launch(void* const* d_in, const int* in_sizes, int n_in,
                              void* d_out, int out_size, void* d_ws, size_t ws_size,
                              hipStream_t stream) {
    const float* x    = (const float*)d_in[0];
    const int*   wq3  = (const int*)d_in[1];
    const void*  wn   = (const void*)d_in[2];
    const float* bias = (const float*)d_in[3];
    float*       out  = (float*)d_out;

    // out receives exactly 2 atomic partials per element -> zero it first
    hipMemsetAsync(d_out, 0, (size_t)BATCH * OUT_F * sizeof(float), stream);

    if (ws_size >= (size_t)(2 * 128 * 64 * 8 * 2)) {   // 256 KB packed-A
        unsigned short* apk = (unsigned short*)d_ws;
        pack_x_kernel<<<dim3(64), dim3(256), 0, stream>>>(x, apk);
        l3b_main<true><<<dim3(512), dim3(256), 0, stream>>>(x, wq3, wn, bias, out, apk);
    } else {
        l3b_main<false><<<dim3(512), dim3(256), 0, stream>>>(x, wq3, wn, bias, out, nullptr);
    }
}

// Round 7
// 17.218 us; speedup vs baseline: 1.3042x; 1.1500x over previous
//
#include <hip/hip_runtime.h>
#include <hip/hip_fp16.h>

#define IN_F   4096
#define OUT_F  4096
#define BATCH  32
#define NGPR   512          // groups per output row
#define BN     16           // output rows per block
#define NW     8            // waves per block
#define QPITCH 1540         // dwords per q-row in LDS (1536 + 4; 1540%32==4 -> 2-way banks)
#define NPITCH 516          // floats per norm-row in LDS (512 + 4)

typedef float f32x4  __attribute__((ext_vector_type(4)));
typedef short short8 __attribute__((ext_vector_type(8)));

__device__ __forceinline__ unsigned short f2bf_u(float f) {
    return __builtin_bit_cast(unsigned short, (__bf16)f);   // RNE via v_cvt
}

__device__ __forceinline__ void gload16(const void* gsrc, void* lds) {
    __builtin_amdgcn_global_load_lds(
        (const __attribute__((address_space(1))) void*)gsrc,
        (__attribute__((address_space(3))) void*)lds, 16, 0, 0);
}

// ---- pack x[32][4096] fp32 -> A-fragment-layout bf16 in d_ws ----
// apk unit u = (a*128 + s)*64 + q*16 + cl  holds bf16 x[a*16+cl][s*32+q*8 .. +8]
__global__ __launch_bounds__(256)
void pack_x_kernel(const float* __restrict__ x, unsigned short* __restrict__ apk)
{
    const int tau = blockIdx.x * 256 + threadIdx.x;   // 0..16383
    const int row = tau >> 9;                         // 0..31
    const int c   = tau & 511;                        // 8-float chunk within row
    const float4 lo = *reinterpret_cast<const float4*>(&x[row * IN_F + c * 8]);
    const float4 hi = *reinterpret_cast<const float4*>(&x[row * IN_F + c * 8 + 4]);
    union { unsigned short us[8]; uint4 v; } pk;
    pk.us[0] = f2bf_u(lo.x); pk.us[1] = f2bf_u(lo.y);
    pk.us[2] = f2bf_u(lo.z); pk.us[3] = f2bf_u(lo.w);
    pk.us[4] = f2bf_u(hi.x); pk.us[5] = f2bf_u(hi.y);
    pk.us[6] = f2bf_u(hi.z); pk.us[7] = f2bf_u(hi.w);
    const int a = row >> 4, cl = row & 15, s = c >> 2, q = c & 3;
    const int unit = (a * 128 + s) * 64 + q * 16 + cl;
    *reinterpret_cast<uint4*>(&apk[unit * 8]) = pk.v;
}

template<bool PACKED>
__global__ __launch_bounds__(512, 2)
void l3b_main(const float* __restrict__ x,
              const int* __restrict__ wq3,
              const void* __restrict__ wnorm_raw,
              const float* __restrict__ bias,
              float* __restrict__ out,
              const unsigned short* __restrict__ apk)
{
    __shared__ unsigned int qls[BN * QPITCH];   // raw q dwords, 96 KB + pad
    __shared__ float        nrm[BN][NPITCH];    // fp32 scales, 33 KB
    __shared__ float        red[NW][BATCH][17]; // 17.4 KB

    const int tid   = threadIdx.x;
    const int w     = tid >> 6;
    const int lane  = tid & 63;
    const int nbase = blockIdx.x * BN;

    const int q  = lane >> 4;   // 0..3
    const int cl = lane & 15;   // 0..15

    // ---- weight_norm dtype probe (deterministic, wave-uniform) ----
    // 0 = float32, 1 = float16 (raw), 2 = bfloat16
    const unsigned short* wn16  = (const unsigned short*)wnorm_raw;
    const float*          wn32  = (const float*)wnorm_raw;
    const unsigned int*   wnu32 = (const unsigned int*)wnorm_raw;
    int mode;
    {
        const unsigned short h = wn16[lane];
        const float v16 = __half2float(__builtin_bit_cast(__half, h));
        const float vbf = __builtin_bit_cast(float, (unsigned int)h << 16);
        const float v32 = wn32[lane];
        const int c16 = __popcll(__ballot(v16 > 0.0095f && v16 < 1.0005f));
        const int cbf = __popcll(__ballot(vbf > 0.0095f && vbf < 1.0005f));
        const int c32 = __popcll(__ballot(v32 > 0.0095f && v32 < 1.0005f));
        if (c16 >= c32 && c16 >= cbf) {
            mode = 1;
        } else if (c32 > cbf + 8) {
            mode = 0;
        } else if (cbf > c32 + 8) {
            mode = 2;
        } else {
            const int z = __popcll(__ballot((wnu32[lane] & 0x1FFFu) == 0u));
            mode = (z >= 48) ? 0 : 2;
        }
    }

    // ---- stage raw q panel (16 rows x 1536 dwords, contiguous in global) ----
    // wave w stages rows 2w and 2w+1; every instruction is 1 KB contiguous in
    // BOTH global and LDS (global_load_lds-legal), fully dense (16 lines/instr).
    {
        const int* qg = wq3 + (long)nbase * 1536;
        #pragma unroll
        for (int rr = 0; rr < 2; ++rr) {
            const int row = w * 2 + rr;
            #pragma unroll
            for (int i = 0; i < 6; ++i) {
                const int off = i * 256 + lane * 4;
                gload16(qg + (long)row * 1536 + off, &qls[row * QPITCH + off]);
            }
        }
    }

    // ---- stage norms -> fp32 LDS (rows contiguous in global, dense) ----
    if (mode == 0) {
        const float* nb = wn32 + (long)nbase * NGPR;
        #pragma unroll
        for (int j = 0; j < 4; ++j) {
            const int f = j * 2048 + tid * 4;
            const float4 v = *reinterpret_cast<const float4*>(nb + f);
            *reinterpret_cast<float4*>(&nrm[f >> 9][f & 511]) = v;
        }
    } else {
        const unsigned short* nb = wn16 + (long)nbase * NGPR;
        #pragma unroll
        for (int j = 0; j < 2; ++j) {
            const int f = j * 4096 + tid * 8;
            union { unsigned short us[8]; uint4 v; } u;
            u.v = *reinterpret_cast<const uint4*>(nb + f);
            float4 f0, f1;
            if (mode == 1) {
                f0.x = __half2float(__builtin_bit_cast(__half, u.us[0]));
                f0.y = __half2float(__builtin_bit_cast(__half, u.us[1]));
                f0.z = __half2float(__builtin_bit_cast(__half, u.us[2]));
                f0.w = __half2float(__builtin_bit_cast(__half, u.us[3]));
                f1.x = __half2float(__builtin_bit_cast(__half, u.us[4]));
                f1.y = __half2float(__builtin_bit_cast(__half, u.us[5]));
                f1.z = __half2float(__builtin_bit_cast(__half, u.us[6]));
                f1.w = __half2float(__builtin_bit_cast(__half, u.us[7]));
            } else {
                f0.x = __builtin_bit_cast(float, (unsigned)u.us[0] << 16);
                f0.y = __builtin_bit_cast(float, (unsigned)u.us[1] << 16);
                f0.z = __builtin_bit_cast(float, (unsigned)u.us[2] << 16);
                f0.w = __builtin_bit_cast(float, (unsigned)u.us[3] << 16);
                f1.x = __builtin_bit_cast(float, (unsigned)u.us[4] << 16);
                f1.y = __builtin_bit_cast(float, (unsigned)u.us[5] << 16);
                f1.z = __builtin_bit_cast(float, (unsigned)u.us[6] << 16);
                f1.w = __builtin_bit_cast(float, (unsigned)u.us[7] << 16);
            }
            const int row = f >> 9, col = f & 511;
            *reinterpret_cast<float4*>(&nrm[row][col])     = f0;
            *reinterpret_cast<float4*>(&nrm[row][col + 4]) = f1;
        }
    }

    __syncthreads();   // drains vmcnt (global_load_lds) + lgkm

    // ---- compute: wave w owns ksteps s = w*16 .. w*16+15 ----
    f32x4 acc0 = {0.f, 0.f, 0.f, 0.f};
    f32x4 acc1 = {0.f, 0.f, 0.f, 0.f};

    #pragma unroll 4
    for (int i = 0; i < 16; ++i) {
        const int s = w * 16 + i;
        const int g = s * 4 + q;

        // re-assemble 24-bit group word from 3 raw dwords (one byte each)
        const int qb = cl * QPITCH + g * 3;
        const unsigned d0 = qls[qb];
        const unsigned d1 = qls[qb + 1];
        const unsigned d2 = qls[qb + 2];
        const unsigned val = (d0 & 0xFFu) | ((d1 & 0xFFu) << 8) | ((d2 & 0xFFu) << 16);

        const float n  = nrm[cl][g];
        const float av = n * 0.285714285714285714f;   // 2n/7
        union { unsigned short us[8]; short8 v; } B;
        #pragma unroll
        for (int e = 0; e < 8; ++e) {
            const float qf = (float)((val >> (3 * e)) & 7u);
            B.us[e] = f2bf_u(fmaf(qf, av, -n));
        }

        short8 A0, A1;
        if (PACKED) {
            A0 = *reinterpret_cast<const short8*>(&apk[(s * 64 + lane) * 8]);
            A1 = *reinterpret_cast<const short8*>(&apk[((128 + s) * 64 + lane) * 8]);
        } else {
            const int kg = s * 32 + q * 8;
            const float4 a0lo = *reinterpret_cast<const float4*>(&x[cl        * IN_F + kg]);
            const float4 a0hi = *reinterpret_cast<const float4*>(&x[cl        * IN_F + kg + 4]);
            const float4 a1lo = *reinterpret_cast<const float4*>(&x[(cl + 16) * IN_F + kg]);
            const float4 a1hi = *reinterpret_cast<const float4*>(&x[(cl + 16) * IN_F + kg + 4]);
            union { unsigned short us[8]; short8 v; } U0, U1;
            U0.us[0] = f2bf_u(a0lo.x); U0.us[1] = f2bf_u(a0lo.y);
            U0.us[2] = f2bf_u(a0lo.z); U0.us[3] = f2bf_u(a0lo.w);
            U0.us[4] = f2bf_u(a0hi.x); U0.us[5] = f2bf_u(a0hi.y);
            U0.us[6] = f2bf_u(a0hi.z); U0.us[7] = f2bf_u(a0hi.w);
            U1.us[0] = f2bf_u(a1lo.x); U1.us[1] = f2bf_u(a1lo.y);
            U1.us[2] = f2bf_u(a1lo.z); U1.us[3] = f2bf_u(a1lo.w);
            U1.us[4] = f2bf_u(a1hi.x); U1.us[5] = f2bf_u(a1hi.y);
            U1.us[6] = f2bf_u(a1hi.z); U1.us[7] = f2bf_u(a1hi.w);
            A0 = U0.v; A1 = U1.v;
        }

        acc0 = __builtin_amdgcn_mfma_f32_16x16x32_bf16(A0, B.v, acc0, 0, 0, 0);
        acc1 = __builtin_amdgcn_mfma_f32_16x16x32_bf16(A1, B.v, acc1, 0, 0, 0);
    }

    // ---- cross-wave K-reduction + bias + store ----
    #pragma unroll
    for (int i = 0; i < 4; ++i) {
        red[w][q * 4 + i][cl]      = acc0[i];
        red[w][16 + q * 4 + i][cl] = acc1[i];
    }
    __syncthreads();
    {
        const int m  = tid >> 4;   // 0..31
        const int nl = tid & 15;
        float ssum = 0.f;
        #pragma unroll
        for (int wv = 0; wv < NW; ++wv) ssum += red[wv][m][nl];
        out[m * OUT_F + nbase + nl] = ssum + bias[nbase + nl];
    }
}

extern "C" void kernel_launch(void* const* d_in, const int* in_sizes, int n_in,
                              void* d_out, int out_size, void* d_ws, size_t ws_size,
                              hipStream_t stream) {
    const float* x    = (const float*)d_in[0];
    const int*   wq3  = (const int*)d_in[1];
    const void*  wn   = (const void*)d_in[2];
    const float* bias = (const float*)d_in[3];
    float*       out  = (float*)d_out;

    if (ws_size >= (size_t)(2 * 128 * 64 * 8 * 2)) {   // 256 KB packed-A
        unsigned short* apk = (unsigned short*)d_ws;
        pack_x_kernel<<<dim3(64), dim3(256), 0, stream>>>(x, apk);
        l3b_main<true><<<dim3(OUT_F / BN), dim3(512), 0, stream>>>(x, wq3, wn, bias, out, apk);
    } else {
        l3b_main<false><<<dim3(OUT_F / BN), dim3(512), 0, stream>>>(x, wq3, wn, bias, out, nullptr);
    }
}